// Round 5
// baseline (278.403 us; speedup 1.0000x reference)
//
#include <hip/hip_runtime.h>
#include <hip/hip_bf16.h>

// TasteNet fused MLP: z(N,64) -> h1(128) relu -> h2(128) relu -> b(12) ->
// clamp/taste/segment-sum epilogue with x(N,9) -> out(N,3) fp32.
//
// R5 vs R4: R4 killed the spill (WRITE 76->6.1 MB) and hit 99 us, but at
// 1 wave/SIMD (occupancy 10.6%) with prefetch distance ~400 cyc vs ~900 cyc
// HBM latency -> every tile stalls on vmcnt with no TLP to cover it.
// Changes:
//  - 2-tile-deep z prefetch (zvA/zvB ring, loop unrolled x2): issue->use
//    distance ~2000 cyc >> HBM latency. +32 regs, fine under (256,1).
//  - layer-3 accumulator split into two 4-deep MFMA chains (+8 adds):
//    removes ~128 cyc of exposed dependent-MFMA latency per tile.
//  - x loads issued at tile top (before z-prefetch issue) so the epilogue
//    waits at vmcnt(8), keeping the prefetch in flight.

typedef __bf16 bf16x8 __attribute__((ext_vector_type(8)));
typedef float  f32x16 __attribute__((ext_vector_type(16)));
typedef unsigned int uint2v __attribute__((ext_vector_type(2)));
typedef unsigned int uint4v __attribute__((ext_vector_type(4)));

#define MFMA32(a, b, c) __builtin_amdgcn_mfma_f32_32x32x16_bf16((a), (b), (c), 0, 0, 0)

// ---- LDS layout (bf16 element offsets), verified R2-R4 ----
#define SW3 0        // 12 rows x 128 elts (row reads m=12..31 overrun into SW1;
                     // garbage feats land in acc3 regs never read)
#define SW1 1536     // 128 rows x 64 elts (128 B row, xor-swizzled 16B chunks)
#define SW2 9728     // 128 rows x 128 elts (256 B row, swizzled)
#define SB1 26112
#define SB2 26240
#define SB3 26368
#define SMEM_ELTS 26384   // 52768 B

#define NBLK    512
#define NTILE   16384          // 524288 rows / 32
#define WSTRIDE (NBLK * 4)     // 2048 waves -> exactly 8 tiles each

__device__ __forceinline__ unsigned pkbf(float lo, float hi) {
  unsigned short lb = __builtin_bit_cast(unsigned short, (__bf16)lo);
  unsigned short hb = __builtin_bit_cast(unsigned short, (__bf16)hi);
  return ((unsigned)hb << 16) | (unsigned)lb;
}

// 32x32 C-layout -> next-layer B-frag via one permlane32_swap per packed pair.
// Verified R1-R4 (absmax 5.9e-3).
template <int SUB>
__device__ __forceinline__ bf16x8 mk_bfrag(const f32x16 h) {
  constexpr int B = SUB * 8;
  unsigned p01 = pkbf(h[B + 0], h[B + 1]);
  unsigned p23 = pkbf(h[B + 2], h[B + 3]);
  unsigned p45 = pkbf(h[B + 4], h[B + 5]);
  unsigned p67 = pkbf(h[B + 6], h[B + 7]);
  unsigned d0, d1, d2, d3;
#if __has_builtin(__builtin_amdgcn_permlane32_swap)
  uint2v r1 = __builtin_amdgcn_permlane32_swap(p01, p45, false, false);
  uint2v r2 = __builtin_amdgcn_permlane32_swap(p23, p67, false, false);
  d0 = r1[0]; d2 = r1[1];
  d1 = r2[0]; d3 = r2[1];
#else
  int hi = (threadIdx.x >> 5) & 1;
  unsigned sp01 = (unsigned)__shfl_xor((int)p01, 32, 64);
  unsigned sp23 = (unsigned)__shfl_xor((int)p23, 32, 64);
  unsigned sp45 = (unsigned)__shfl_xor((int)p45, 32, 64);
  unsigned sp67 = (unsigned)__shfl_xor((int)p67, 32, 64);
  d0 = hi ? sp45 : p01;
  d2 = hi ? p45  : sp01;
  d1 = hi ? sp67 : p23;
  d3 = hi ? p67  : sp23;
#endif
  uint4v t; t[0] = d0; t[1] = d1; t[2] = d2; t[3] = d3;
  return __builtin_bit_cast(bf16x8, t);
}

__device__ __forceinline__ bf16x8 ldw(const __bf16* sm, int byteoff) {
  return *(const bf16x8*)((const char*)sm + byteoff);
}

// bias A-frag: A[m][0] = v on q=0 lanes; MFMA'd against ones-B (B[0][:]=1)
__device__ __forceinline__ bf16x8 biasA(__bf16 v) {
  bf16x8 f;
  #pragma unroll
  for (int i = 0; i < 8; ++i) f[i] = (__bf16)0.0f;
  f[0] = v;
  return f;
}

__global__ __launch_bounds__(256, 1)
void tastenet_kernel(const float* __restrict__ x, const float* __restrict__ z,
                     const float* __restrict__ W1, const float* __restrict__ b1,
                     const float* __restrict__ W2, const float* __restrict__ b2,
                     const float* __restrict__ W3, const float* __restrict__ b3,
                     float* __restrict__ out) {
  __shared__ __align__(16) __bf16 sm[SMEM_ELTS];
  const int tid = threadIdx.x;
  unsigned* smw = (unsigned*)sm;

  // ---- stage weights transposed + bf16, xor-swizzled 16B chunks ----
  for (int i = tid; i < 4096; i += 256) {           // W1 (64x128)
    int m = i & 127, k = (i >> 7) * 2;
    smw[SW1 / 2 + m * 32 + (((k >> 3) ^ (m & 7)) << 2) + ((k >> 1) & 3)] =
        pkbf(W1[k * 128 + m], W1[(k + 1) * 128 + m]);
  }
  for (int i = tid; i < 8192; i += 256) {           // W2 (128x128)
    int m = i & 127, k = (i >> 7) * 2;
    smw[SW2 / 2 + m * 64 + (((k >> 3) ^ (m & 7)) << 2) + ((k >> 1) & 3)] =
        pkbf(W2[k * 128 + m], W2[(k + 1) * 128 + m]);
  }
  for (int i = tid; i < 768; i += 256) {            // W3 (128x12)
    int kk = i / 12, m = i - kk * 12, k = kk * 2;
    smw[SW3 / 2 + m * 64 + (((k >> 3) ^ (m & 7)) << 2) + ((k >> 1) & 3)] =
        pkbf(W3[k * 12 + m], W3[(k + 1) * 12 + m]);
  }
  if (tid < 128) { sm[SB1 + tid] = (__bf16)b1[tid]; sm[SB2 + tid] = (__bf16)b2[tid]; }
  if (tid < 12)  sm[SB3 + tid] = (__bf16)b3[tid];
  __syncthreads();

  const int wave = tid >> 6;
  const int lane = tid & 63;
  const int q    = lane >> 5;
  const int n    = lane & 31;
  const int s8   = n & 7;
  const int eq   = q ^ (s8 & 1);
  const int sh   = s8 >> 1;

  // per-lane swizzled A-frag byte offsets (verified R2-R4)
  int t1k[4], t2k[8];
  #pragma unroll
  for (int kt = 0; kt < 4; ++kt) t1k[kt] = n * 128 + eq * 16 + 32 * (kt ^ sh);
  #pragma unroll
  for (int kt = 0; kt < 8; ++kt)
    t2k[kt] = n * 256 + eq * 16 + 32 * ((kt & 3) ^ sh) + 128 * (kt >> 2);

  __bf16 bv1[4], bv2[4], bv3;
  #pragma unroll
  for (int f = 0; f < 4; ++f) {
    bv1[f] = (q == 0) ? sm[SB1 + f * 32 + n] : (__bf16)0.0f;
    bv2[f] = (q == 0) ? sm[SB2 + f * 32 + n] : (__bf16)0.0f;
  }
  bv3 = (q == 0 && n < 12) ? sm[SB3 + n] : (__bf16)0.0f;

  bf16x8 ones;
  #pragma unroll
  for (int i = 0; i < 8; ++i) ones[i] = (__bf16)0.0f;
  if (q == 0) ones[0] = (__bf16)1.0f;

  const int wid = blockIdx.x * 4 + wave;

  // ---- 2-deep z prefetch ring ----
  float4 zvA[8], zvB[8];
  {
    const float* zr = z + ((long)wid * 32 + n) * 64;
    #pragma unroll
    for (int kt = 0; kt < 4; ++kt) {
      zvA[2 * kt]     = *(const float4*)(zr + kt * 16 + q * 8);
      zvA[2 * kt + 1] = *(const float4*)(zr + kt * 16 + q * 8 + 4);
    }
    const float* zr2 = z + ((long)(wid + WSTRIDE) * 32 + n) * 64;
    #pragma unroll
    for (int kt = 0; kt < 4; ++kt) {
      zvB[2 * kt]     = *(const float4*)(zr2 + kt * 16 + q * 8);
      zvB[2 * kt + 1] = *(const float4*)(zr2 + kt * 16 + q * 8 + 4);
    }
  }

  auto body = [&](int t, float4* zv) {
    const long row = (long)t * 32 + n;

    // x for this tile: issued first so the epilogue's x-wait leaves the
    // z-prefetch (issued below) outstanding.
    const float* xr = x + row * 9;
    float xv0 = xr[q * 4 + 0], xv1 = xr[q * 4 + 1];
    float xv2 = xr[q * 4 + 2], xv3 = xr[q * 4 + 3];
    float xv4 = xr[8];

    // z -> bf16 B-frags (zv regs free after this)
    bf16x8 bz[4];
    #pragma unroll
    for (int kt = 0; kt < 4; ++kt) {
      float4 a = zv[2 * kt], b = zv[2 * kt + 1];
      bf16x8 f;
      f[0] = (__bf16)a.x; f[1] = (__bf16)a.y; f[2] = (__bf16)a.z; f[3] = (__bf16)a.w;
      f[4] = (__bf16)b.x; f[5] = (__bf16)b.y; f[6] = (__bf16)b.z; f[7] = (__bf16)b.w;
      bz[kt] = f;
    }

    // prefetch z two tiles ahead into the ring slot just freed
    if (t + 2 * WSTRIDE < NTILE) {
      const float* zr = z + ((long)(t + 2 * WSTRIDE) * 32 + n) * 64;
      #pragma unroll
      for (int kt = 0; kt < 4; ++kt) {
        zv[2 * kt]     = *(const float4*)(zr + kt * 16 + q * 8);
        zv[2 * kt + 1] = *(const float4*)(zr + kt * 16 + q * 8 + 4);
      }
    }

    // ---- layer 1: ft pairs, pack immediately ----
    bf16x8 bf2[8];
    #pragma unroll
    for (int fp = 0; fp < 2; ++fp) {
      f32x16 aA, aB;
      #pragma unroll
      for (int i = 0; i < 16; ++i) { aA[i] = 0.0f; aB[i] = 0.0f; }
      #pragma unroll
      for (int kt = 0; kt < 4; ++kt) {
        aA = MFMA32(ldw(sm, SW1 * 2 + (2 * fp + 0) * 4096 + t1k[kt]), bz[kt], aA);
        aB = MFMA32(ldw(sm, SW1 * 2 + (2 * fp + 1) * 4096 + t1k[kt]), bz[kt], aB);
      }
      aA = MFMA32(biasA(bv1[2 * fp + 0]), ones, aA);
      aB = MFMA32(biasA(bv1[2 * fp + 1]), ones, aB);
      #pragma unroll
      for (int i = 0; i < 16; ++i) { aA[i] = fmaxf(aA[i], 0.0f); aB[i] = fmaxf(aB[i], 0.0f); }
      bf2[4 * fp + 0] = mk_bfrag<0>(aA);
      bf2[4 * fp + 1] = mk_bfrag<1>(aA);
      bf2[4 * fp + 2] = mk_bfrag<0>(aB);
      bf2[4 * fp + 3] = mk_bfrag<1>(aB);
    }

    // ---- layer 2: ft pairs ----
    bf16x8 bf3[8];
    #pragma unroll
    for (int fp = 0; fp < 2; ++fp) {
      f32x16 aA, aB;
      #pragma unroll
      for (int i = 0; i < 16; ++i) { aA[i] = 0.0f; aB[i] = 0.0f; }
      #pragma unroll
      for (int kt = 0; kt < 8; ++kt) {
        aA = MFMA32(ldw(sm, SW2 * 2 + (2 * fp + 0) * 8192 + t2k[kt]), bf2[kt], aA);
        aB = MFMA32(ldw(sm, SW2 * 2 + (2 * fp + 1) * 8192 + t2k[kt]), bf2[kt], aB);
      }
      aA = MFMA32(biasA(bv2[2 * fp + 0]), ones, aA);
      aB = MFMA32(biasA(bv2[2 * fp + 1]), ones, aB);
      #pragma unroll
      for (int i = 0; i < 16; ++i) { aA[i] = fmaxf(aA[i], 0.0f); aB[i] = fmaxf(aB[i], 0.0f); }
      bf3[4 * fp + 0] = mk_bfrag<0>(aA);
      bf3[4 * fp + 1] = mk_bfrag<1>(aA);
      bf3[4 * fp + 2] = mk_bfrag<0>(aB);
      bf3[4 * fp + 3] = mk_bfrag<1>(aB);
    }

    // ---- layer 3: two independent 4-deep chains (halves exposed latency) ----
    f32x16 a3a, a3b;
    #pragma unroll
    for (int i = 0; i < 16; ++i) { a3a[i] = 0.0f; a3b[i] = 0.0f; }
    #pragma unroll
    for (int kt = 0; kt < 4; ++kt) {
      a3a = MFMA32(ldw(sm, SW3 * 2 + t2k[kt]), bf3[kt], a3a);
      a3b = MFMA32(ldw(sm, SW3 * 2 + t2k[kt + 4]), bf3[kt + 4], a3b);
    }
    a3a = MFMA32(biasA(bv3), ones, a3a);

    // ---- epilogue (only regs 0..7 carry real features) ----
    float t0 = a3a[0] + a3b[0], t1 = a3a[1] + a3b[1];
    float t2 = a3a[2] + a3b[2], t3 = a3a[3] + a3b[3];
    float t4 = a3a[4] + a3b[4], t5 = a3a[5] + a3b[5];
    float t6 = a3a[6] + a3b[6], t7 = a3a[7] + a3b[7];
    float o0 = 0.f, o1 = 0.f, o2 = 0.f, g1v = 0.f, g2v = 0.f;
    if (q == 0) {
      t0 = fminf(t0, 0.0f); t1 = fminf(t1, 0.0f);
      t2 = fminf(t2, 0.0f); t3 = fminf(t3, 0.0f);
      t4 = fminf(t4, 0.0f);                       // feat 8
      o0 = xv0 * t0 + xv1 * t1 + xv2 * t2 + t5;   // seg0 + I9
      o1 = xv3 * t3 + t6;                         // seg1 part + I10
      o2 = xv4 * t4 + t7;                         // seg2 part + I11
    } else {
      t0 = fminf(t0, 0.0f); t1 = fminf(t1, 0.0f); // feats 4,5
      t3 = fminf(t3, 0.0f);                       // feat 7 (feat 6 passes)
      g1v = xv0 * t0 + xv1 * t1;
      g2v = xv2 * t2 + xv3 * t3;
    }
    float a1v = __shfl_xor(g1v, 32, 64);
    float a2v = __shfl_xor(g2v, 32, 64);
    if (q == 0) {
      float* op = out + row * 3;
      op[0] = o0;
      op[1] = o1 + a1v;
      op[2] = o2 + a2v;
    }
  };

  #pragma unroll 1
  for (int t = wid; t < NTILE; t += 2 * WSTRIDE) {
    body(t, zvA);
    body(t + WSTRIDE, zvB);
  }
}

extern "C" void kernel_launch(void* const* d_in, const int* in_sizes, int n_in,
                              void* d_out, int out_size, void* d_ws, size_t ws_size,
                              hipStream_t stream) {
  const float* x  = (const float*)d_in[0];
  const float* z  = (const float*)d_in[1];
  const float* W1 = (const float*)d_in[2];
  const float* b1 = (const float*)d_in[3];
  const float* W2 = (const float*)d_in[4];
  const float* b2 = (const float*)d_in[5];
  const float* W3 = (const float*)d_in[6];
  const float* b3 = (const float*)d_in[7];
  tastenet_kernel<<<dim3(NBLK), dim3(256), 0, stream>>>(
      x, z, W1, b1, W2, b2, W3, b3, (float*)d_out);
}

// Round 6
// 253.175 us; speedup vs baseline: 1.0996x; 1.0996x over previous
//
#include <hip/hip_runtime.h>
#include <hip/hip_bf16.h>

// TasteNet fused MLP: z(N,64) -> h1(128) relu -> h2(128) relu -> b(12) ->
// clamp/taste/segment-sum epilogue with x(N,9) -> out(N,3) fp32.
//
// R6 vs R5/R4: R5's 2-deep prefetch ring (+32 regs) hit the 256 arch-VGPR
// ceiling -> spill returned (WRITE 22.5 MB), 130 us. R4 (no spill, 236 regs)
// was latency-serialized at ~1 wave/SIMD. R6 = R4 structure with:
//  - early prefetch: next-tile z issued right after bz conversion (same ring
//    slot, zero extra regs) -> issue->use distance ~ full body.
//  - layer 3 fused into layer 2's fp-loop: bf3[8] buffer (32 regs at peak)
//    eliminated; each fp-pair's 4 fragments are MFMA'd into acc3 and die.
//  - grid 768 (LDS 53KB allows 3 blocks/CU) for more resident waves.

typedef __bf16 bf16x8 __attribute__((ext_vector_type(8)));
typedef float  f32x16 __attribute__((ext_vector_type(16)));
typedef unsigned int uint2v __attribute__((ext_vector_type(2)));
typedef unsigned int uint4v __attribute__((ext_vector_type(4)));

#define MFMA32(a, b, c) __builtin_amdgcn_mfma_f32_32x32x16_bf16((a), (b), (c), 0, 0, 0)

// ---- LDS layout (bf16 element offsets), verified R2-R5 ----
#define SW3 0        // 12 rows x 128 elts (row reads m=12..31 overrun into SW1;
                     // garbage feats land in acc3 regs never read)
#define SW1 1536     // 128 rows x 64 elts (128 B row, xor-swizzled 16B chunks)
#define SW2 9728     // 128 rows x 128 elts (256 B row, swizzled)
#define SB1 26112
#define SB2 26240
#define SB3 26368
#define SMEM_ELTS 26384   // 52768 B

#define NBLK    768
#define NTILE   16384          // 524288 rows / 32
#define WSTRIDE (NBLK * 4)

__device__ __forceinline__ unsigned pkbf(float lo, float hi) {
  unsigned short lb = __builtin_bit_cast(unsigned short, (__bf16)lo);
  unsigned short hb = __builtin_bit_cast(unsigned short, (__bf16)hi);
  return ((unsigned)hb << 16) | (unsigned)lb;
}

// 32x32 C-layout -> next-layer B-frag via one permlane32_swap per packed pair.
// Verified R1-R5 (absmax 5.9e-3).
template <int SUB>
__device__ __forceinline__ bf16x8 mk_bfrag(const f32x16 h) {
  constexpr int B = SUB * 8;
  unsigned p01 = pkbf(h[B + 0], h[B + 1]);
  unsigned p23 = pkbf(h[B + 2], h[B + 3]);
  unsigned p45 = pkbf(h[B + 4], h[B + 5]);
  unsigned p67 = pkbf(h[B + 6], h[B + 7]);
  unsigned d0, d1, d2, d3;
#if __has_builtin(__builtin_amdgcn_permlane32_swap)
  uint2v r1 = __builtin_amdgcn_permlane32_swap(p01, p45, false, false);
  uint2v r2 = __builtin_amdgcn_permlane32_swap(p23, p67, false, false);
  d0 = r1[0]; d2 = r1[1];
  d1 = r2[0]; d3 = r2[1];
#else
  int hi = (threadIdx.x >> 5) & 1;
  unsigned sp01 = (unsigned)__shfl_xor((int)p01, 32, 64);
  unsigned sp23 = (unsigned)__shfl_xor((int)p23, 32, 64);
  unsigned sp45 = (unsigned)__shfl_xor((int)p45, 32, 64);
  unsigned sp67 = (unsigned)__shfl_xor((int)p67, 32, 64);
  d0 = hi ? sp45 : p01;
  d2 = hi ? p45  : sp01;
  d1 = hi ? sp67 : p23;
  d3 = hi ? p67  : sp23;
#endif
  uint4v t; t[0] = d0; t[1] = d1; t[2] = d2; t[3] = d3;
  return __builtin_bit_cast(bf16x8, t);
}

__device__ __forceinline__ bf16x8 ldw(const __bf16* sm, int byteoff) {
  return *(const bf16x8*)((const char*)sm + byteoff);
}

// bias A-frag: A[m][0] = v on q=0 lanes; MFMA'd against ones-B (B[0][:]=1)
__device__ __forceinline__ bf16x8 biasA(__bf16 v) {
  bf16x8 f;
  #pragma unroll
  for (int i = 0; i < 8; ++i) f[i] = (__bf16)0.0f;
  f[0] = v;
  return f;
}

__global__ __launch_bounds__(256, 1)
void tastenet_kernel(const float* __restrict__ x, const float* __restrict__ z,
                     const float* __restrict__ W1, const float* __restrict__ b1,
                     const float* __restrict__ W2, const float* __restrict__ b2,
                     const float* __restrict__ W3, const float* __restrict__ b3,
                     float* __restrict__ out) {
  __shared__ __align__(16) __bf16 sm[SMEM_ELTS];
  const int tid = threadIdx.x;
  unsigned* smw = (unsigned*)sm;

  // ---- stage weights transposed + bf16, xor-swizzled 16B chunks ----
  for (int i = tid; i < 4096; i += 256) {           // W1 (64x128)
    int m = i & 127, k = (i >> 7) * 2;
    smw[SW1 / 2 + m * 32 + (((k >> 3) ^ (m & 7)) << 2) + ((k >> 1) & 3)] =
        pkbf(W1[k * 128 + m], W1[(k + 1) * 128 + m]);
  }
  for (int i = tid; i < 8192; i += 256) {           // W2 (128x128)
    int m = i & 127, k = (i >> 7) * 2;
    smw[SW2 / 2 + m * 64 + (((k >> 3) ^ (m & 7)) << 2) + ((k >> 1) & 3)] =
        pkbf(W2[k * 128 + m], W2[(k + 1) * 128 + m]);
  }
  for (int i = tid; i < 768; i += 256) {            // W3 (128x12)
    int kk = i / 12, m = i - kk * 12, k = kk * 2;
    smw[SW3 / 2 + m * 64 + (((k >> 3) ^ (m & 7)) << 2) + ((k >> 1) & 3)] =
        pkbf(W3[k * 12 + m], W3[(k + 1) * 12 + m]);
  }
  if (tid < 128) { sm[SB1 + tid] = (__bf16)b1[tid]; sm[SB2 + tid] = (__bf16)b2[tid]; }
  if (tid < 12)  sm[SB3 + tid] = (__bf16)b3[tid];
  __syncthreads();

  const int wave = tid >> 6;
  const int lane = tid & 63;
  const int q    = lane >> 5;
  const int n    = lane & 31;
  const int s8   = n & 7;
  const int eq   = q ^ (s8 & 1);
  const int sh   = s8 >> 1;

  // per-lane swizzled A-frag byte offsets (verified R2-R5)
  int t1k[4], t2k[8];
  #pragma unroll
  for (int kt = 0; kt < 4; ++kt) t1k[kt] = n * 128 + eq * 16 + 32 * (kt ^ sh);
  #pragma unroll
  for (int kt = 0; kt < 8; ++kt)
    t2k[kt] = n * 256 + eq * 16 + 32 * ((kt & 3) ^ sh) + 128 * (kt >> 2);

  __bf16 bv1[4], bv2[4], bv3;
  #pragma unroll
  for (int f = 0; f < 4; ++f) {
    bv1[f] = (q == 0) ? sm[SB1 + f * 32 + n] : (__bf16)0.0f;
    bv2[f] = (q == 0) ? sm[SB2 + f * 32 + n] : (__bf16)0.0f;
  }
  bv3 = (q == 0 && n < 12) ? sm[SB3 + n] : (__bf16)0.0f;

  bf16x8 ones;
  #pragma unroll
  for (int i = 0; i < 8; ++i) ones[i] = (__bf16)0.0f;
  if (q == 0) ones[0] = (__bf16)1.0f;

  const int wid = blockIdx.x * 4 + wave;

  // prefetch z for first tile (single ring slot, 32 regs)
  float4 zv[8];
  {
    const float* zr = z + ((long)wid * 32 + n) * 64;
    #pragma unroll
    for (int kt = 0; kt < 4; ++kt) {
      zv[2 * kt]     = *(const float4*)(zr + kt * 16 + q * 8);
      zv[2 * kt + 1] = *(const float4*)(zr + kt * 16 + q * 8 + 4);
    }
  }

  #pragma unroll 1
  for (int t = wid; t < NTILE; t += WSTRIDE) {
    const long row = (long)t * 32 + n;

    // x for this tile: issued before the z-prefetch so the epilogue's x-wait
    // leaves the prefetch outstanding.
    const float* xr = x + row * 9;
    float xv0 = xr[q * 4 + 0], xv1 = xr[q * 4 + 1];
    float xv2 = xr[q * 4 + 2], xv3 = xr[q * 4 + 3];
    float xv4 = xr[8];

    // z -> bf16 B-frags (frees the zv ring slot)
    bf16x8 bz[4];
    #pragma unroll
    for (int kt = 0; kt < 4; ++kt) {
      float4 a = zv[2 * kt], b = zv[2 * kt + 1];
      bf16x8 f;
      f[0] = (__bf16)a.x; f[1] = (__bf16)a.y; f[2] = (__bf16)a.z; f[3] = (__bf16)a.w;
      f[4] = (__bf16)b.x; f[5] = (__bf16)b.y; f[6] = (__bf16)b.z; f[7] = (__bf16)b.w;
      bz[kt] = f;
    }

    // EARLY prefetch of next tile's z into the just-freed slot:
    // issue->use distance = layers 1-3 + epilogue (~full body).
    if (t + WSTRIDE < NTILE) {
      const float* zr = z + ((long)(t + WSTRIDE) * 32 + n) * 64;
      #pragma unroll
      for (int kt = 0; kt < 4; ++kt) {
        zv[2 * kt]     = *(const float4*)(zr + kt * 16 + q * 8);
        zv[2 * kt + 1] = *(const float4*)(zr + kt * 16 + q * 8 + 4);
      }
    }

    // ---- layer 1: ft pairs, pack immediately ----
    bf16x8 bf2[8];
    #pragma unroll
    for (int fp = 0; fp < 2; ++fp) {
      f32x16 aA, aB;
      #pragma unroll
      for (int i = 0; i < 16; ++i) { aA[i] = 0.0f; aB[i] = 0.0f; }
      #pragma unroll
      for (int kt = 0; kt < 4; ++kt) {
        aA = MFMA32(ldw(sm, SW1 * 2 + (2 * fp + 0) * 4096 + t1k[kt]), bz[kt], aA);
        aB = MFMA32(ldw(sm, SW1 * 2 + (2 * fp + 1) * 4096 + t1k[kt]), bz[kt], aB);
      }
      aA = MFMA32(biasA(bv1[2 * fp + 0]), ones, aA);
      aB = MFMA32(biasA(bv1[2 * fp + 1]), ones, aB);
      #pragma unroll
      for (int i = 0; i < 16; ++i) { aA[i] = fmaxf(aA[i], 0.0f); aB[i] = fmaxf(aB[i], 0.0f); }
      bf2[4 * fp + 0] = mk_bfrag<0>(aA);
      bf2[4 * fp + 1] = mk_bfrag<1>(aA);
      bf2[4 * fp + 2] = mk_bfrag<0>(aB);
      bf2[4 * fp + 3] = mk_bfrag<1>(aB);
    }

    // ---- layer 2 with layer 3 fused: each fp-pair's four h2 fragments are
    // consumed by 4 layer-3 MFMAs immediately (no bf3 buffer) ----
    f32x16 acc3;
    #pragma unroll
    for (int i = 0; i < 16; ++i) acc3[i] = 0.0f;
    #pragma unroll
    for (int fp = 0; fp < 2; ++fp) {
      f32x16 aA, aB;
      #pragma unroll
      for (int i = 0; i < 16; ++i) { aA[i] = 0.0f; aB[i] = 0.0f; }
      #pragma unroll
      for (int kt = 0; kt < 8; ++kt) {
        aA = MFMA32(ldw(sm, SW2 * 2 + (2 * fp + 0) * 8192 + t2k[kt]), bf2[kt], aA);
        aB = MFMA32(ldw(sm, SW2 * 2 + (2 * fp + 1) * 8192 + t2k[kt]), bf2[kt], aB);
      }
      aA = MFMA32(biasA(bv2[2 * fp + 0]), ones, aA);
      aB = MFMA32(biasA(bv2[2 * fp + 1]), ones, aB);
      #pragma unroll
      for (int i = 0; i < 16; ++i) { aA[i] = fmaxf(aA[i], 0.0f); aB[i] = fmaxf(aB[i], 0.0f); }
      // h2 features 64*fp + [0,64) == layer-3 K block kt = 4*fp + [0,4)
      acc3 = MFMA32(ldw(sm, SW3 * 2 + t2k[4 * fp + 0]), mk_bfrag<0>(aA), acc3);
      acc3 = MFMA32(ldw(sm, SW3 * 2 + t2k[4 * fp + 1]), mk_bfrag<1>(aA), acc3);
      acc3 = MFMA32(ldw(sm, SW3 * 2 + t2k[4 * fp + 2]), mk_bfrag<0>(aB), acc3);
      acc3 = MFMA32(ldw(sm, SW3 * 2 + t2k[4 * fp + 3]), mk_bfrag<1>(aB), acc3);
    }
    acc3 = MFMA32(biasA(bv3), ones, acc3);

    // ---- epilogue (only regs 0..7 carry real features) ----
    float t0 = acc3[0], t1 = acc3[1], t2 = acc3[2], t3 = acc3[3];
    float t4 = acc3[4], t5 = acc3[5], t6 = acc3[6], t7 = acc3[7];
    float o0 = 0.f, o1 = 0.f, o2 = 0.f, g1v = 0.f, g2v = 0.f;
    if (q == 0) {
      t0 = fminf(t0, 0.0f); t1 = fminf(t1, 0.0f);
      t2 = fminf(t2, 0.0f); t3 = fminf(t3, 0.0f);
      t4 = fminf(t4, 0.0f);                       // feat 8
      o0 = xv0 * t0 + xv1 * t1 + xv2 * t2 + t5;   // seg0 + I9
      o1 = xv3 * t3 + t6;                         // seg1 part + I10
      o2 = xv4 * t4 + t7;                         // seg2 part + I11
    } else {
      t0 = fminf(t0, 0.0f); t1 = fminf(t1, 0.0f); // feats 4,5
      t3 = fminf(t3, 0.0f);                       // feat 7 (feat 6 passes)
      g1v = xv0 * t0 + xv1 * t1;
      g2v = xv2 * t2 + xv3 * t3;
    }
    float a1v = __shfl_xor(g1v, 32, 64);
    float a2v = __shfl_xor(g2v, 32, 64);
    if (q == 0) {
      float* op = out + row * 3;
      op[0] = o0;
      op[1] = o1 + a1v;
      op[2] = o2 + a2v;
    }
  }
}

extern "C" void kernel_launch(void* const* d_in, const int* in_sizes, int n_in,
                              void* d_out, int out_size, void* d_ws, size_t ws_size,
                              hipStream_t stream) {
  const float* x  = (const float*)d_in[0];
  const float* z  = (const float*)d_in[1];
  const float* W1 = (const float*)d_in[2];
  const float* b1 = (const float*)d_in[3];
  const float* W2 = (const float*)d_in[4];
  const float* b2 = (const float*)d_in[5];
  const float* W3 = (const float*)d_in[6];
  const float* b3 = (const float*)d_in[7];
  tastenet_kernel<<<dim3(NBLK), dim3(256), 0, stream>>>(
      x, z, W1, b1, W2, b2, W3, b3, (float*)d_out);
}